// Round 4
// baseline (5211.491 us; speedup 1.0000x reference)
//
#include <hip/hip_runtime.h>
#include <hip/hip_bf16.h>

// ---------------------------------------------------------------------------
// BotGraphSAGE round 4: barrier-free dense layers.
//  - K-loop has NO __syncthreads (avoids the compiler's vmcnt(0) barrier
//    drain): X rows read per-thread (each thread consumes 2 full cache lines
//    per 32-k chunk), double-buffered in VGPRs; W broadcast from LDS via
//    wave-uniform ds_read_b128 (no per-k s_load latency).
//  - CSR build (multi-block scan + bucketed scatter) and 64-d aggregations
//    unchanged from round 3.
// ---------------------------------------------------------------------------

#define BK_SHIFT 8
#define BK_SIZE 256

__global__ void hist_kernel(const int* __restrict__ dst, int* __restrict__ cnt, int E) {
    int e = blockIdx.x * 256 + threadIdx.x;
    if (e < E) atomicAdd(&cnt[dst[e]], 1);
}

__global__ void scan_reduce_kernel(const int* __restrict__ cnt, int* __restrict__ bsum, int n) {
    int t = threadIdx.x;
    int i = blockIdx.x * 256 + t;
    int v = (i < n) ? cnt[i] : 0;
#pragma unroll
    for (int s = 32; s > 0; s >>= 1) v += __shfl_down(v, s, 64);
    __shared__ int ws[4];
    if ((t & 63) == 0) ws[t >> 6] = v;
    __syncthreads();
    if (t == 0) bsum[blockIdx.x] = ws[0] + ws[1] + ws[2] + ws[3];
}

__global__ void scan_mid_kernel(const int* __restrict__ bsum, int* __restrict__ bbase, int nb) {
    __shared__ int sd[256];
    __shared__ int carry;
    int t = threadIdx.x;
    if (t == 0) carry = 0;
    __syncthreads();
    for (int base = 0; base < nb; base += 256) {
        int v = (base + t < nb) ? bsum[base + t] : 0;
        sd[t] = v;
        __syncthreads();
        for (int d = 1; d < 256; d <<= 1) {
            int x = (t >= d) ? sd[t - d] : 0;
            __syncthreads();
            sd[t] += x;
            __syncthreads();
        }
        if (base + t < nb) bbase[base + t] = carry + sd[t] - v;
        __syncthreads();
        if (t == 0) carry += sd[255];
        __syncthreads();
    }
}

__global__ void scan_final_kernel(const int* __restrict__ cnt, const int* __restrict__ bbase,
                                  int* __restrict__ off, float* __restrict__ invc, int n) {
    __shared__ int sd[256];
    int t = threadIdx.x;
    int i = blockIdx.x * 256 + t;
    int v = (i < n) ? cnt[i] : 0;
    sd[t] = v;
    __syncthreads();
    for (int d = 1; d < 256; d <<= 1) {
        int x = (t >= d) ? sd[t - d] : 0;
        __syncthreads();
        sd[t] += x;
        __syncthreads();
    }
    if (i < n) {
        off[i + 1] = bbase[blockIdx.x] + sd[t];
        invc[i] = 1.0f / fmaxf((float)v, 1.0f);
    }
    if (i == 0) off[0] = 0;
}

__global__ void init_gcur_kernel(const int* __restrict__ off, int* __restrict__ gcur, int nb, int n) {
    int b = blockIdx.x * 256 + threadIdx.x;
    if (b < nb) gcur[b] = off[b * BK_SIZE];
}

__global__ __launch_bounds__(256) void bucketA_kernel(const int* __restrict__ src,
    const int* __restrict__ dst, int* __restrict__ gcur,
    uint2* __restrict__ pairs, int E, int nb)
{
    __shared__ int lcnt[256];
    __shared__ int lbase[256];
    int t = threadIdx.x;
    int cbase = blockIdx.x * 4096;
    lcnt[t] = 0;
    __syncthreads();
#pragma unroll
    for (int r = 0; r < 16; ++r) {
        int e = cbase + r * 256 + t;
        if (e < E) atomicAdd(&lcnt[dst[e] >> BK_SHIFT], 1);
    }
    __syncthreads();
    if (t < nb && lcnt[t] > 0) lbase[t] = atomicAdd(&gcur[t], lcnt[t]);
    lcnt[t] = 0;
    __syncthreads();
#pragma unroll
    for (int r = 0; r < 16; ++r) {
        int e = cbase + r * 256 + t;
        if (e < E) {
            int d = dst[e];
            int bk = d >> BK_SHIFT;
            int pos = lbase[bk] + atomicAdd(&lcnt[bk], 1);
            pairs[pos] = make_uint2((unsigned)src[e], (unsigned)d);
        }
    }
}

__global__ __launch_bounds__(256) void bucketB_kernel(const uint2* __restrict__ pairs,
    const int* __restrict__ off, int* __restrict__ csr, int n)
{
    __shared__ int lcur[BK_SIZE];
    int t = threadIdx.x;
    int b = blockIdx.x;
    int d0 = b * BK_SIZE;
    int dlim = min(BK_SIZE, n - d0);
    if (t < dlim) lcur[t] = off[d0 + t];
    __syncthreads();
    int start = off[d0];
    int end = off[min(d0 + BK_SIZE, n)];
    for (int i = start + t; i < end; i += 256) {
        uint2 p = pairs[i];
        int pos = atomicAdd(&lcur[p.y & (BK_SIZE - 1)], 1);
        csr[pos] = (int)p.x;
    }
}

// ---------------------------------------------------------------------------
// f1a: des[N,768] @ W_des[768,32], split-K x4, barrier-free K-loop.
// Thread = node; 6 chunks of 32 k; X double-buffered in VGPRs; W in LDS.
// ---------------------------------------------------------------------------
__global__ __launch_bounds__(256) void f1a_kernel(const float* __restrict__ des,
    const float* __restrict__ W, float* __restrict__ part, int n)
{
    __shared__ __align__(16) float sW[192 * 32];
    int t = threadIdx.x;
    int kb0 = blockIdx.y * 192;
    // stage W[kb0:kb0+192][32] -> LDS (coalesced)
    for (int i = t; i < 192 * 8; i += 256) {
        int k = i >> 3, c4 = (i & 7) * 4;
        *reinterpret_cast<float4*>(&sW[k * 32 + c4]) =
            *reinterpret_cast<const float4*>(W + (size_t)(kb0 + k) * 32 + c4);
    }
    int node = blockIdx.x * 256 + t;
    int ln = node < n ? node : n - 1;
    const float* xrow = des + (size_t)ln * 768 + kb0;

    float4 b0[8], b1[8];
#pragma unroll
    for (int r = 0; r < 8; ++r) b0[r] = *reinterpret_cast<const float4*>(xrow + r * 4);
    __syncthreads();

    float acc[32];
#pragma unroll
    for (int c = 0; c < 32; ++c) acc[c] = 0.f;

#pragma unroll 2
    for (int ch = 0; ch < 6; ++ch) {
        const float4* cur = (ch & 1) ? b1 : b0;
        float4* nxt = (ch & 1) ? b0 : b1;
        if (ch + 1 < 6) {
#pragma unroll
            for (int r = 0; r < 8; ++r)
                nxt[r] = *reinterpret_cast<const float4*>(xrow + (ch + 1) * 32 + r * 4);
        }
        const float* wb = sW + ch * 1024;
#pragma unroll
        for (int k4 = 0; k4 < 8; ++k4) {
            float4 xv = cur[k4];
            float xa[4] = {xv.x, xv.y, xv.z, xv.w};
#pragma unroll
            for (int kk = 0; kk < 4; ++kk) {
                float x = xa[kk];
                const float* wr = wb + (k4 * 4 + kk) * 32;
#pragma unroll
                for (int c4 = 0; c4 < 8; ++c4) {
                    float4 w = *reinterpret_cast<const float4*>(wr + c4 * 4);
                    acc[c4 * 4 + 0] = fmaf(x, w.x, acc[c4 * 4 + 0]);
                    acc[c4 * 4 + 1] = fmaf(x, w.y, acc[c4 * 4 + 1]);
                    acc[c4 * 4 + 2] = fmaf(x, w.z, acc[c4 * 4 + 2]);
                    acc[c4 * 4 + 3] = fmaf(x, w.w, acc[c4 * 4 + 3]);
                }
            }
        }
    }
    if (node < n) {
        float* po = part + ((size_t)blockIdx.y * n + node) * 32;
#pragma unroll
        for (int c4 = 0; c4 < 8; ++c4)
            *reinterpret_cast<float4*>(po + c4 * 4) =
                make_float4(acc[c4 * 4], acc[c4 * 4 + 1], acc[c4 * 4 + 2], acc[c4 * 4 + 3]);
    }
}

__global__ void f1c_kernel(const float* __restrict__ part, const float* __restrict__ b,
                           float* __restrict__ Xout, int n) {
    int idx = blockIdx.x * 256 + threadIdx.x;
    if (idx >= n * 32) return;
    int node = idx >> 5, c = idx & 31;
    size_t stride = (size_t)n * 32;
    float v = part[idx] + part[stride + idx] + part[2 * stride + idx] + part[3 * stride + idx] + b[c];
    v = v > 0.f ? v : 0.01f * v;
    Xout[(size_t)node * 128 + c] = v;
}

__global__ __launch_bounds__(256) void f1b_kernel(const float* __restrict__ nump,
    const float* __restrict__ catp,
    const float* __restrict__ Wn, const float* __restrict__ bn,
    const float* __restrict__ Wc, const float* __restrict__ bc,
    float* __restrict__ Xout, int n)
{
    int idx = blockIdx.x * 256 + threadIdx.x;
    if (idx >= n * 84) return;
    int node = idx / 84;
    int c = idx - node * 84;
    float v;
    if (c < 42) {
        v = bn[c];
#pragma unroll
        for (int k = 0; k < 4; ++k) v += nump[node * 4 + k] * Wn[k * 42 + c];
    } else {
        int o = c - 42;
        v = bc[o];
#pragma unroll
        for (int k = 0; k < 3; ++k) v += catp[node * 3 + k] * Wc[k * 42 + o];
    }
    v = v > 0.f ? v : 0.01f * v;
    Xout[(size_t)node * 128 + 32 + c] = v;
}

// ---------------------------------------------------------------------------
// Barrier-free node-per-lane GEMM: X[N,128] @ W[K,128] -> Y[N,128].
// blockIdx.y = cs (32-col group). W staged in LDS (zero-padded past K).
// MODE 0: WA[K][128]; MODE 1: col-concat WA|WB [K][64]x2;
// MODE 2: row-concat [WA[64][128]; WB[64][128]].
// BIASM 0: none; 1: bias[128]; 2: bias[64] on cols >= 64. ACT 0/1/2.
// ---------------------------------------------------------------------------
template<int K, int MODE, int ACT, int BIASM>
__global__ __launch_bounds__(256) void gemm_bf_kernel(
    const float* __restrict__ X,
    const float* __restrict__ WA, const float* __restrict__ WB,
    const float* __restrict__ bias,
    float* __restrict__ Y, int n)
{
    constexpr int NCH = (K + 31) / 32;
    __shared__ __align__(16) float sW[NCH * 1024];
    int t = threadIdx.x;
    int cs = blockIdx.y;
    for (int i = t; i < NCH * 256; i += 256) {
        int k = i >> 3, c4 = (i & 7) * 4;
        float4 w = make_float4(0.f, 0.f, 0.f, 0.f);
        if (k < K) {
            const float* src;
            if (MODE == 0)      src = WA + (size_t)k * 128 + cs * 32;
            else if (MODE == 1) src = (cs < 2) ? WA + (size_t)k * 64 + cs * 32
                                               : WB + (size_t)k * 64 + (cs - 2) * 32;
            else                src = (k < 64) ? WA + (size_t)k * 128 + cs * 32
                                               : WB + (size_t)(k - 64) * 128 + cs * 32;
            w = *reinterpret_cast<const float4*>(src + c4);
        }
        *reinterpret_cast<float4*>(&sW[(size_t)i * 4]) = w;
    }
    int node = blockIdx.x * 256 + t;
    int ln = node < n ? node : n - 1;
    const float* xrow = X + (size_t)ln * 128;

    float4 b0[8], b1[8];
#pragma unroll
    for (int r = 0; r < 8; ++r) b0[r] = *reinterpret_cast<const float4*>(xrow + r * 4);
    __syncthreads();

    float acc[32];
#pragma unroll
    for (int c = 0; c < 32; ++c) acc[c] = 0.f;

#pragma unroll 2
    for (int ch = 0; ch < NCH; ++ch) {
        const float4* cur = (ch & 1) ? b1 : b0;
        float4* nxt = (ch & 1) ? b0 : b1;
        if (ch + 1 < NCH) {
#pragma unroll
            for (int r = 0; r < 8; ++r)
                nxt[r] = *reinterpret_cast<const float4*>(xrow + (ch + 1) * 32 + r * 4);
        }
        const float* wb = sW + ch * 1024;
#pragma unroll
        for (int k4 = 0; k4 < 8; ++k4) {
            float4 xv = cur[k4];
            float xa[4] = {xv.x, xv.y, xv.z, xv.w};
#pragma unroll
            for (int kk = 0; kk < 4; ++kk) {
                float x = xa[kk];
                const float* wr = wb + (k4 * 4 + kk) * 32;
#pragma unroll
                for (int c4 = 0; c4 < 8; ++c4) {
                    float4 w = *reinterpret_cast<const float4*>(wr + c4 * 4);
                    acc[c4 * 4 + 0] = fmaf(x, w.x, acc[c4 * 4 + 0]);
                    acc[c4 * 4 + 1] = fmaf(x, w.y, acc[c4 * 4 + 1]);
                    acc[c4 * 4 + 2] = fmaf(x, w.z, acc[c4 * 4 + 2]);
                    acc[c4 * 4 + 3] = fmaf(x, w.w, acc[c4 * 4 + 3]);
                }
            }
        }
    }

    if (node < n) {
        int c0 = cs * 32;
        float* yp = Y + (size_t)node * 128 + c0;
#pragma unroll
        for (int c = 0; c < 32; ++c) {
            float v = acc[c];
            if (BIASM == 1) v += bias[c0 + c];
            if (BIASM == 2) { if (cs >= 2) v += bias[c0 - 64 + c]; }
            if (ACT == 1) v = fmaxf(v, 0.f);
            else if (ACT == 2) v = v > 0.f ? v : 0.01f * v;
            acc[c] = v;
        }
#pragma unroll
        for (int c4 = 0; c4 < 8; ++c4)
            *reinterpret_cast<float4*>(yp + c4 * 4) =
                make_float4(acc[c4 * 4], acc[c4 * 4 + 1], acc[c4 * 4 + 2], acc[c4 * 4 + 3]);
    }
}

// SAGE layer-a epilogue: H[dst] = relu(mean_agg(Y[:,0:64]) + Y[dst,64:128])
__global__ __launch_bounds__(256) void agg_a_kernel(const float* __restrict__ Y,
    const int* __restrict__ off, const int* __restrict__ csr,
    const float* __restrict__ invc, float* __restrict__ H, int n)
{
    int wid = (blockIdx.x * 256 + threadIdx.x) >> 6;
    int f = threadIdx.x & 63;
    if (wid >= n) return;
    float root = Y[(size_t)wid * 128 + 64 + f];
    int b = off[wid], e = off[wid + 1];
    float acc = 0.f;
    for (; b + 8 <= e; b += 8) {
        int idx[8];
#pragma unroll
        for (int j = 0; j < 8; ++j) idx[j] = csr[b + j];
        float v[8];
#pragma unroll
        for (int j = 0; j < 8; ++j) v[j] = Y[(size_t)idx[j] * 128 + f];
#pragma unroll
        for (int j = 0; j < 8; ++j) acc += v[j];
    }
    for (; b + 2 <= e; b += 2) {
        int s0 = csr[b], s1 = csr[b + 1];
        acc += Y[(size_t)s0 * 128 + f] + Y[(size_t)s1 * 128 + f];
    }
    for (; b < e; ++b) acc += Y[(size_t)csr[b] * 128 + f];
    float v = acc * invc[wid] + root;
    H[(size_t)wid * 64 + f] = fmaxf(v, 0.f);
}

// SAGE layer-b pre-GEMM: Z[dst,0:64] = mean_agg(H), Z[dst,64:128] = H[dst]
__global__ __launch_bounds__(256) void agg_b_kernel(const float* __restrict__ H,
    const int* __restrict__ off, const int* __restrict__ csr,
    const float* __restrict__ invc, float* __restrict__ Z, int n)
{
    int wid = (blockIdx.x * 256 + threadIdx.x) >> 6;
    int f = threadIdx.x & 63;
    if (wid >= n) return;
    float root = H[(size_t)wid * 64 + f];
    int b = off[wid], e = off[wid + 1];
    float acc = 0.f;
    for (; b + 8 <= e; b += 8) {
        int idx[8];
#pragma unroll
        for (int j = 0; j < 8; ++j) idx[j] = csr[b + j];
        float v[8];
#pragma unroll
        for (int j = 0; j < 8; ++j) v[j] = H[(size_t)idx[j] * 64 + f];
#pragma unroll
        for (int j = 0; j < 8; ++j) acc += v[j];
    }
    for (; b + 2 <= e; b += 2) {
        int s0 = csr[b], s1 = csr[b + 1];
        acc += H[(size_t)s0 * 64 + f] + H[(size_t)s1 * 64 + f];
    }
    for (; b < e; ++b) acc += H[(size_t)csr[b] * 64 + f];
    Z[(size_t)wid * 128 + f] = acc * invc[wid];
    Z[(size_t)wid * 128 + 64 + f] = root;
}

// Head stage 2: out[node] = H[node,0:128] . W2[128,2] + b2; one wave per node.
__global__ __launch_bounds__(256) void head2_kernel(const float* __restrict__ H,
    const float* __restrict__ W2, const float* __restrict__ b2,
    float* __restrict__ out, int n)
{
    int l = threadIdx.x & 63;
    int node = (blockIdx.x * 256 + threadIdx.x) >> 6;
    if (node >= n) return;
    float x0 = H[(size_t)node * 128 + l];
    float x1 = H[(size_t)node * 128 + 64 + l];
    float a0 = x0 * W2[l * 2]     + x1 * W2[(64 + l) * 2];
    float a1 = x0 * W2[l * 2 + 1] + x1 * W2[(64 + l) * 2 + 1];
#pragma unroll
    for (int s = 32; s > 0; s >>= 1) {
        a0 += __shfl_down(a0, s, 64);
        a1 += __shfl_down(a1, s, 64);
    }
    if (l == 0) {
        out[(size_t)node * 2]     = a0 + b2[0];
        out[(size_t)node * 2 + 1] = a1 + b2[1];
    }
}

extern "C" void kernel_launch(void* const* d_in, const int* in_sizes, int n_in,
                              void* d_out, int out_size, void* d_ws, size_t ws_size,
                              hipStream_t stream)
{
    const float* des   = (const float*)d_in[0];
    const float* nump  = (const float*)d_in[2];
    const float* catp  = (const float*)d_in[3];
    const int*   ei    = (const int*)d_in[4];
    const float* W_des = (const float*)d_in[5];  const float* b_des = (const float*)d_in[6];
    const float* W_num = (const float*)d_in[7];  const float* b_num = (const float*)d_in[8];
    const float* W_cat = (const float*)d_in[9];  const float* b_cat = (const float*)d_in[10];
    const float* W_in  = (const float*)d_in[11]; const float* b_in  = (const float*)d_in[12];
    const float* s1a_Wl = (const float*)d_in[13]; const float* s1a_bl = (const float*)d_in[14];
    const float* s1a_Wr = (const float*)d_in[15];
    const float* s1b_Wl = (const float*)d_in[16]; const float* s1b_bl = (const float*)d_in[17];
    const float* s1b_Wr = (const float*)d_in[18];
    const float* s2a_Wl = (const float*)d_in[19]; const float* s2a_bl = (const float*)d_in[20];
    const float* s2a_Wr = (const float*)d_in[21];
    const float* s2b_Wl = (const float*)d_in[22]; const float* s2b_bl = (const float*)d_in[23];
    const float* s2b_Wr = (const float*)d_in[24];
    const float* W_o1  = (const float*)d_in[25]; const float* b_o1 = (const float*)d_in[26];
    const float* W_o2  = (const float*)d_in[27]; const float* b_o2 = (const float*)d_in[28];
    float* out = (float*)d_out;

    int N = in_sizes[0] / 768;
    int E = in_sizes[4] / 2;
    const int* srcp = ei;
    const int* dstp = ei + E;
    int NB = (N + BK_SIZE - 1) >> BK_SHIFT;
    int NBLK = (N + 255) / 256;

    float* P0 = (float*)d_ws;
    float* P1 = P0 + (size_t)128 * N;
    float* P2 = P1 + (size_t)128 * N;   // f1a partials / agg temp / pair buffer
    int* cnt   = (int*)(P2 + (size_t)128 * N);
    int* off   = cnt + N;
    float* invc = (float*)(off + (N + 1));
    int* csr   = (int*)(invc + N);
    int* bsum  = csr + E;
    int* bbase = bsum + NBLK;
    int* gcur  = bbase + NBLK;
    uint2* pairs = (uint2*)P2;

    // --- CSR build ---
    hipMemsetAsync(cnt, 0, (size_t)N * sizeof(int), stream);
    hist_kernel<<<(E + 255) / 256, 256, 0, stream>>>(dstp, cnt, E);
    scan_reduce_kernel<<<NBLK, 256, 0, stream>>>(cnt, bsum, N);
    scan_mid_kernel<<<1, 256, 0, stream>>>(bsum, bbase, NBLK);
    scan_final_kernel<<<NBLK, 256, 0, stream>>>(cnt, bbase, off, invc, N);
    init_gcur_kernel<<<(NB + 255) / 256, 256, 0, stream>>>(off, gcur, NB, N);
    bucketA_kernel<<<(E + 4095) / 4096, 256, 0, stream>>>(srcp, dstp, gcur, pairs, E, NB);
    bucketB_kernel<<<NB, 256, 0, stream>>>(pairs, off, csr, N);

    int nbn = (N + 255) / 256;
    dim3 gemm_grid(nbn, 4);
    int nbw = (N + 3) / 4;

    // --- Front MLP ---
    f1a_kernel<<<dim3(nbn, 4), 256, 0, stream>>>(des, W_des, P2, N);
    f1b_kernel<<<(N * 84 + 255) / 256, 256, 0, stream>>>(nump, catp, W_num, b_num, W_cat, b_cat, P0, N);
    f1c_kernel<<<(N * 32 + 255) / 256, 256, 0, stream>>>(P2, b_des, P0, N);
    gemm_bf_kernel<116, 0, 2, 1><<<gemm_grid, 256, 0, stream>>>(P0, W_in, nullptr, b_in, P1, N);

    // --- SAGE block 1 ---
    gemm_bf_kernel<128, 1, 0, 2><<<gemm_grid, 256, 0, stream>>>(P1, s1a_Wl, s1a_Wr, s1a_bl, P0, N);
    agg_a_kernel<<<nbw, 256, 0, stream>>>(P0, off, csr, invc, P2, N);
    agg_b_kernel<<<nbw, 256, 0, stream>>>(P2, off, csr, invc, P1, N);
    gemm_bf_kernel<128, 2, 1, 1><<<gemm_grid, 256, 0, stream>>>(P1, s1b_Wl, s1b_Wr, s1b_bl, P0, N);

    // --- SAGE block 2 ---
    gemm_bf_kernel<128, 1, 0, 2><<<gemm_grid, 256, 0, stream>>>(P0, s2a_Wl, s2a_Wr, s2a_bl, P1, N);
    agg_a_kernel<<<nbw, 256, 0, stream>>>(P1, off, csr, invc, P2, N);
    agg_b_kernel<<<nbw, 256, 0, stream>>>(P2, off, csr, invc, P0, N);
    gemm_bf_kernel<128, 2, 1, 1><<<gemm_grid, 256, 0, stream>>>(P0, s2b_Wl, s2b_Wr, s2b_bl, P1, N);

    // --- Head ---
    gemm_bf_kernel<128, 0, 2, 1><<<gemm_grid, 256, 0, stream>>>(P1, W_o1, nullptr, b_o1, P2, N);
    head2_kernel<<<(N + 3) / 4, 256, 0, stream>>>(P2, W_o2, b_o2, out, N);
}